// Round 1
// baseline (6280.981 us; speedup 1.0000x reference)
//
#include <hip/hip_runtime.h>
#include <hip/hip_bf16.h>

// ---------------------------------------------------------------------------
// RPN pipeline:
//  1. conv3x3  : fp32 tiled conv 2048->1024, pad 1, + bias  -> x[1024][2500]
//  2. heads    : 1x1 convs (36 reg + 18 cls channels)       -> ho[2500][56]
//  3. decode   : box decode + clip + min-size filter        -> roi, sort keys
//  4. bitonic  : descending stable sort of 32768 64-bit keys (top-6000 used)
//  5. gather   : sorted boxes + valid flags
//  6. nmsmask  : 6000x6000 IoU suppression bitmask (94 words/row)
//  7. nmsscan  : single-wave greedy scan (<=300 keeps) + write output
// ---------------------------------------------------------------------------

#define NPOS 2500
#define NBOX 22500
#define NSORT 32768
#define NPRE 6000
#define NWORDS 94       // ceil(6000/64)
#define NPOST 300

// ---------------- 1. conv 3x3, 2048 -> 1024, 50x50, pad 1 ------------------
// Block: 256 threads = 16 (co rows) x 16 (pos cols). Tile: 64 co x 64 linear
// positions. Each thread: 4 co x 4 consecutive positions. K-chunk = 8 ci.
// LDS: Ws[72][65] (8ci*9taps x 64co, stride 65 kills write conflicts),
//      Fs[8][5][52] (5 input rows w/ halo, zero-padded borders).
__global__ __launch_bounds__(256) void conv3x3(
    const float* __restrict__ feat, const float* __restrict__ W1,
    const float* __restrict__ b1, float* __restrict__ x) {
  __shared__ float Ws[72 * 65];
  __shared__ float Fs[8 * 5 * 52];
  const int tid = threadIdx.x;
  const int tr = tid >> 4, tc = tid & 15;
  const int pt = blockIdx.x;      // 40 position tiles
  const int ct = blockIdx.y;      // 16 co tiles
  const int p0 = pt * 64;
  const int co0 = ct * 64;
  const int y0 = p0 / 50;

  int rb0[4];
  bool pok[4];
  #pragma unroll
  for (int j = 0; j < 4; ++j) {
    int p = p0 + tc * 4 + j;
    pok[j] = (p < NPOS);
    int pc = p < NPOS ? p : (NPOS - 1);
    int y = pc / 50, xx = pc % 50;
    rb0[j] = (y - y0) * 52 + xx;  // f addr = ci*260 + rb0 + ky*52 + kx
  }

  float acc[4][4];
  #pragma unroll
  for (int i = 0; i < 4; ++i)
    #pragma unroll
    for (int j = 0; j < 4; ++j) acc[i][j] = 0.f;

  for (int ch = 0; ch < 256; ++ch) {
    const int ci0 = ch * 8;
    __syncthreads();
    // --- stage weights: 4608 = 18*256 elements, 72-float runs per co ---
    const float* wbase = W1 + (size_t)co0 * 18432 + (size_t)ci0 * 9;
    #pragma unroll
    for (int l = 0; l < 18; ++l) {
      int e = tid + l * 256;
      int cor = e / 72, kk = e % 72;
      Ws[kk * 65 + cor] = wbase[(size_t)cor * 18432 + kk];
    }
    // --- stage features: 8 ci x 5 rows x 52 cols, zero-padded ---
    for (int e = tid; e < 2080; e += 256) {
      int ci = e / 260, rem = e % 260;
      int r = rem / 52, xx = rem % 52;
      int iy = y0 - 1 + r, ix = xx - 1;
      float v = 0.f;
      if (iy >= 0 && iy < 50 && ix >= 0 && ix < 50)
        v = feat[(size_t)(ci0 + ci) * NPOS + iy * 50 + ix];
      Fs[e] = v;
    }
    __syncthreads();
    // --- accumulate 8 ci x 9 taps ---
    #pragma unroll
    for (int ci = 0; ci < 8; ++ci) {
      #pragma unroll
      for (int ky = 0; ky < 3; ++ky) {
        #pragma unroll
        for (int kx = 0; kx < 3; ++kx) {
          const int wb = (ci * 9 + ky * 3 + kx) * 65 + tr;
          float w0 = Ws[wb], w1 = Ws[wb + 16], w2 = Ws[wb + 32], w3 = Ws[wb + 48];
          #pragma unroll
          for (int j = 0; j < 4; ++j) {
            float f = Fs[ci * 260 + rb0[j] + ky * 52 + kx];
            acc[0][j] += w0 * f;
            acc[1][j] += w1 * f;
            acc[2][j] += w2 * f;
            acc[3][j] += w3 * f;
          }
        }
      }
    }
  }
  #pragma unroll
  for (int i = 0; i < 4; ++i) {
    int co = co0 + tr + 16 * i;
    float bias = b1[co];
    #pragma unroll
    for (int j = 0; j < 4; ++j) {
      int p = p0 + tc * 4 + j;
      if (pok[j]) x[(size_t)co * NPOS + p] = acc[i][j] + bias;
    }
  }
}

// ---------------- 2. 1x1 conv heads (36 reg + 18 cls channels) -------------
__global__ __launch_bounds__(256) void heads(
    const float* __restrict__ x, const float* __restrict__ Wreg,
    const float* __restrict__ breg, const float* __restrict__ Wcls,
    const float* __restrict__ bcls, float* __restrict__ ho) {
  int p = blockIdx.x * 64 + threadIdx.x;
  int ch = blockIdx.y * 4 + threadIdx.y;
  if (p >= NPOS || ch >= 54) return;
  const float* w = (ch < 36) ? (Wreg + (size_t)ch * 1024)
                             : (Wcls + (size_t)(ch - 36) * 1024);
  float a0 = 0.f, a1 = 0.f, a2 = 0.f, a3 = 0.f;
  for (int c = 0; c < 1024; c += 4) {
    a0 += w[c + 0] * x[(size_t)(c + 0) * NPOS + p];
    a1 += w[c + 1] * x[(size_t)(c + 1) * NPOS + p];
    a2 += w[c + 2] * x[(size_t)(c + 2) * NPOS + p];
    a3 += w[c + 3] * x[(size_t)(c + 3) * NPOS + p];
  }
  float bias = (ch < 36) ? breg[ch] : bcls[ch - 36];
  ho[p * 56 + ch] = (a0 + a1) + (a2 + a3) + bias;
}

// ---------------- 3. decode + min-size filter + sort keys ------------------
__global__ void decodek(const float* __restrict__ ho,
                        const float* __restrict__ anchors,
                        float4* __restrict__ roi,
                        unsigned long long* __restrict__ keys) {
  int i = blockIdx.x * 256 + threadIdx.x;   // grid covers exactly 32768
  if (i >= NBOX) { keys[i] = 0ull; return; }
  int p = i / 9, a = i % 9;
  const float* hp = ho + p * 56;
  float dy = hp[a * 4 + 0], dx = hp[a * 4 + 1];
  float dh = hp[a * 4 + 2], dw = hp[a * 4 + 3];
  float s = hp[36 + a * 2 + 1];
  float ay1 = anchors[i * 4 + 0], ax1 = anchors[i * 4 + 1];
  float ay2 = anchors[i * 4 + 2], ax2 = anchors[i * 4 + 3];
  float ahh = ay2 - ay1, aww = ax2 - ax1;
  float acy = ay1 + 0.5f * ahh, acx = ax1 + 0.5f * aww;
  float cy = dy * ahh + acy, cx = dx * aww + acx;
  float h = expf(dh) * ahh, w = expf(dw) * aww;
  float y1 = fminf(fmaxf(cy - 0.5f * h, 0.f), 800.f);
  float x1 = fminf(fmaxf(cx - 0.5f * w, 0.f), 800.f);
  float y2 = fminf(fmaxf(cy + 0.5f * h, 0.f), 800.f);
  float x2 = fminf(fmaxf(cx + 0.5f * w, 0.f), 800.f);
  bool valid = ((y2 - y1) >= 16.f) && ((x2 - x1) >= 16.f);
  float sc = valid ? s : -__builtin_inff();
  unsigned u = __float_as_uint(sc);
  u = (u & 0x80000000u) ? ~u : (u | 0x80000000u);  // monotone map
  // descending score, ties -> ascending original index (stable argsort)
  keys[i] = ((unsigned long long)u << 32) |
            (unsigned long long)(0xFFFFFFFFu - (unsigned)i);
  roi[i] = make_float4(y1, x1, y2, x2);
}

// ---------------- 4. bitonic sort (descending), 32768 keys -----------------
__global__ __launch_bounds__(1024) void bitonic_local(unsigned long long* keys) {
  __shared__ unsigned long long s[4096];
  int t = threadIdx.x;
  size_t base = (size_t)blockIdx.x * 4096;
  for (int m = t; m < 4096; m += 1024) s[m] = keys[base + m];
  __syncthreads();
  for (int k = 2; k <= 4096; k <<= 1) {
    for (int j = k >> 1; j > 0; j >>= 1) {
      for (int m = t; m < 4096; m += 1024) {
        int l = m ^ j;
        if (l > m) {
          bool desc = (((base + (size_t)m) & (size_t)k) == 0);
          unsigned long long a = s[m], b = s[l];
          if (desc ? (a < b) : (a > b)) { s[m] = b; s[l] = a; }
        }
      }
      __syncthreads();
    }
  }
  for (int m = t; m < 4096; m += 1024) keys[base + m] = s[m];
}

__global__ __launch_bounds__(1024) void bitonic_merge_local(
    unsigned long long* keys, int k) {
  __shared__ unsigned long long s[4096];
  int t = threadIdx.x;
  size_t base = (size_t)blockIdx.x * 4096;
  for (int m = t; m < 4096; m += 1024) s[m] = keys[base + m];
  __syncthreads();
  for (int j = 2048; j > 0; j >>= 1) {
    for (int m = t; m < 4096; m += 1024) {
      int l = m ^ j;
      if (l > m) {
        bool desc = (((base + (size_t)m) & (size_t)k) == 0);
        unsigned long long a = s[m], b = s[l];
        if (desc ? (a < b) : (a > b)) { s[m] = b; s[l] = a; }
      }
    }
    __syncthreads();
  }
  for (int m = t; m < 4096; m += 1024) keys[base + m] = s[m];
}

__global__ void bitonic_global(unsigned long long* keys, int k, int j) {
  int m = blockIdx.x * 256 + threadIdx.x;
  int l = m ^ j;
  if (l > m) {
    bool desc = ((m & k) == 0);
    unsigned long long a = keys[m], b = keys[l];
    if (desc ? (a < b) : (a > b)) { keys[m] = b; keys[l] = a; }
  }
}

// ---------------- 5. gather sorted top-6000 boxes + valid flags ------------
__global__ void gatherk(const unsigned long long* __restrict__ keys,
                        const float4* __restrict__ roi,
                        float4* __restrict__ sbox, int* __restrict__ validArr) {
  int t = blockIdx.x * 256 + threadIdx.x;
  if (t >= NPRE) return;
  unsigned long long k = keys[t];
  unsigned u = (unsigned)(k >> 32);
  int valid = (u > 0x007FFFFFu) ? 1 : 0;  // strictly above -inf key
  float4 b = make_float4(0.f, 0.f, 0.f, 0.f);
  if (valid) {
    int idx = (int)(0xFFFFFFFFu - (unsigned)(k & 0xFFFFFFFFull));
    b = roi[idx];
  }
  sbox[t] = b;
  validArr[t] = valid;
}

// ---------------- 6. NMS suppression bitmask -------------------------------
// box float4 = (y1, x1, y2, x2). mask[i][cb] bit j: box i suppresses cb*64+j.
__global__ __launch_bounds__(64) void nmsmask(
    const float4* __restrict__ sbox, unsigned long long* __restrict__ mask) {
  int rb = blockIdx.x, cb = blockIdx.y;
  int t = threadIdx.x;
  __shared__ float4 cbx[64];
  __shared__ float car[64];
  int jj = cb * 64 + t;
  float4 c = (jj < NPRE) ? sbox[jj] : make_float4(0.f, 0.f, 0.f, 0.f);
  cbx[t] = c;
  car[t] = (c.w - c.y + 1.f) * (c.z - c.x + 1.f);
  __syncthreads();
  int i = rb * 64 + t;
  if (i >= NPRE) return;
  float4 b = sbox[i];
  float ai = (b.w - b.y + 1.f) * (b.z - b.x + 1.f);
  unsigned long long bits = 0ull;
  int nj = min(64, NPRE - cb * 64);
  for (int j = 0; j < nj; ++j) {
    float4 cc = cbx[j];
    float yy1 = fmaxf(b.x, cc.x), xx1 = fmaxf(b.y, cc.y);
    float yy2 = fminf(b.z, cc.z), xx2 = fminf(b.w, cc.w);
    float inter = fmaxf(xx2 - xx1 + 1.f, 0.f) * fmaxf(yy2 - yy1 + 1.f, 0.f);
    float iou = inter / (ai + car[j] - inter);
    if (iou > 0.7f) bits |= (1ull << j);
  }
  mask[(size_t)i * NWORDS + cb] = bits;
}

// ---------------- 7. greedy scan (single wave) + output --------------------
__global__ __launch_bounds__(64) void nmsscan(
    const unsigned long long* __restrict__ mask,
    const int* __restrict__ validArr, const float4* __restrict__ sbox,
    float* __restrict__ out) {
  int t = threadIdx.x;
  __shared__ unsigned long long remv[NWORDS];
  __shared__ int keepIdx[NPOST];
  remv[t] = 0ull;
  if (t + 64 < NWORDS) remv[t + 64] = 0ull;
  __syncthreads();
  int nk = 0;
  for (int wb = 0; wb < NWORDS && nk < NPOST; ++wb) {
    int gi = wb * 64 + t;
    bool v = (gi < NPRE) && (validArr[gi] != 0);
    unsigned long long avail = __ballot(v);
    avail &= ~remv[wb];
    while (avail != 0ull && nk < NPOST) {
      int b = __ffsll((unsigned long long)avail) - 1;  // first = highest score
      int i = wb * 64 + b;
      if (t == 0) keepIdx[nk] = i;
      nk++;
      const unsigned long long* row = mask + (size_t)i * NWORDS;
      remv[t] |= row[t];
      if (t + 64 < NWORDS) remv[t + 64] |= row[t + 64];
      __syncthreads();
      avail &= ~remv[wb];  // self-bit (iou=1) clears b
    }
  }
  __syncthreads();
  for (int r = t; r < NPOST; r += 64) {
    float4 bx = make_float4(0.f, 0.f, 0.f, 0.f);
    if (r < nk) bx = sbox[keepIdx[r]];
    reinterpret_cast<float4*>(out)[r] = bx;
  }
}

// ---------------------------------------------------------------------------
extern "C" void kernel_launch(void* const* d_in, const int* in_sizes, int n_in,
                              void* d_out, int out_size, void* d_ws,
                              size_t ws_size, hipStream_t stream) {
  const float* feat    = (const float*)d_in[0];
  const float* anchors = (const float*)d_in[1];
  const float* W1      = (const float*)d_in[2];
  const float* b1      = (const float*)d_in[3];
  const float* Wreg    = (const float*)d_in[4];
  const float* breg    = (const float*)d_in[5];
  const float* Wcls    = (const float*)d_in[6];
  const float* bcls    = (const float*)d_in[7];

  char* ws = (char*)d_ws;
  float* x                   = (float*)(ws);                  // 10,240,000 B
  float* ho                  = (float*)(ws + 10240000);       //    560,000 B
  float4* roi                = (float4*)(ws + 10800000);      //    360,000 B
  unsigned long long* keys   = (unsigned long long*)(ws + 11160000); // 262,144 B
  float4* sbox               = (float4*)(ws + 11422144);      //     96,256 B
  int* validArr              = (int*)(ws + 11518400);         //     24,064 B
  unsigned long long* mask   = (unsigned long long*)(ws + 11542464); // 4,524,032 B
  float* out = (float*)d_out;

  conv3x3<<<dim3(40, 16), 256, 0, stream>>>(feat, W1, b1, x);
  heads<<<dim3(40, 14), dim3(64, 4), 0, stream>>>(x, Wreg, breg, Wcls, bcls, ho);
  decodek<<<128, 256, 0, stream>>>(ho, anchors, roi, keys);

  bitonic_local<<<8, 1024, 0, stream>>>(keys);
  for (int k = 8192; k <= NSORT; k <<= 1) {
    for (int j = k >> 1; j >= 4096; j >>= 1)
      bitonic_global<<<128, 256, 0, stream>>>(keys, k, j);
    bitonic_merge_local<<<8, 1024, 0, stream>>>(keys, k);
  }

  gatherk<<<24, 256, 0, stream>>>(keys, roi, sbox, validArr);
  nmsmask<<<dim3(NWORDS, NWORDS), 64, 0, stream>>>(sbox, mask);
  nmsscan<<<1, 64, 0, stream>>>(mask, validArr, sbox, out);
}

// Round 2
// 2402.536 us; speedup vs baseline: 2.6143x; 2.6143x over previous
//
#include <hip/hip_runtime.h>
#include <hip/hip_bf16.h>

// ---------------------------------------------------------------------------
// RPN pipeline:
//  0. initx    : x[co][p] = b1[co]  (conv accumulates on top via atomicAdd)
//  1. conv3x3  : fp32 reg-tiled conv 2048->1024, K-split x4  -> x[1024][2500]
//  2. heads    : 1x1 convs (36 reg + 18 cls channels)        -> ho[2500][56]
//  3. decode   : box decode + clip + min-size filter         -> roi, sort keys
//  4. bitonic  : descending stable sort of 32768 64-bit keys
//  5. gather   : sorted boxes + valid flags
//  6. nmsmask  : 6000x6000 IoU suppression bitmask
//  7. nmsscan  : single-wave greedy scan (<=300 keeps) + write output
// ---------------------------------------------------------------------------

#define NPOS 2500
#define NBOX 22500
#define NSORT 32768
#define NPRE 6000
#define NWORDS 94
#define NPOST 300

// ---------------- 0. x init with bias --------------------------------------
__global__ void initx(const float* __restrict__ b1, float* __restrict__ x) {
  int i = blockIdx.x * 256 + threadIdx.x;      // 10000 blocks cover 2.56M
  if (i < 1024 * NPOS) x[i] = b1[i / NPOS];
}

// ---------------- 1. conv 3x3, 2048 -> 1024, 50x50, pad 1 ------------------
// Padded-linear position space: 52x52 zero-padded image, linear index pl;
// output pl valid iff row,col in [1,50]. Tap (ky,kx) input = pl+(ky-1)*52+
// (kx-1) -- pure linear, borders are real zeros (no wrap hazard).
// Block 256 thr: tp=tid&15 (8 consecutive pos each -> 128-pos tile),
//                trt=tid>>4 (4 consecutive co each -> 64-co tile).
// K-chunk = 8 ci; K-split x4 over blockIdx.z; atomicAdd into x.
// Per (ci,ky): load f[0..9] once (b128+b128+b64), reuse across kx;
// Ws[kk][64] read as one b128 per kx -> 88 B/lane per 96 lane-FMA (0.92 B/FMA).
__global__ __launch_bounds__(256) void conv3x3_v2(
    const float* __restrict__ feat, const float* __restrict__ W1,
    float* __restrict__ x) {
  __shared__ float Ws[72 * 64];    // 18,432 B  [kk][co]
  __shared__ float Fs[8 * 236];    //  7,552 B  [ci][padded-linear window]
  const int tid = threadIdx.x;
  const int tp = tid & 15;         // position group (8 pos)
  const int trt = tid >> 4;        // co group (4 co)
  const int q0 = blockIdx.x * 128; // padded-linear tile base (22 tiles)
  const int co0 = blockIdx.y * 64; // 16 co tiles
  const int ks = blockIdx.z;       // K-split 0..3

  float acc[4][8];
  #pragma unroll
  for (int c = 0; c < 4; ++c)
    #pragma unroll
    for (int j = 0; j < 8; ++j) acc[c][j] = 0.f;

  // weight staging assignment: thread owns co-run [wco..wco+3], kk = wkk+16*l
  const int wco = (tid & 15) * 4;
  const int wkk = tid >> 4;        // 0..15

  for (int ch = 0; ch < 64; ++ch) {
    const int ci0 = (ks * 64 + ch) * 8;
    __syncthreads();
    // --- stage weights: all (co,kk) covered exactly once; 8 threads with the
    // same co-run interleave kk stride 16 -> every 64B line fully used via L1.
    #pragma unroll
    for (int c = 0; c < 4; ++c) {
      const float* wp = W1 + (size_t)(co0 + wco + c) * 18432 + ci0 * 9;
      #pragma unroll
      for (int l = 0; l < 5; ++l) {
        int kk = wkk + 16 * l;
        if (kk < 72) Ws[kk * 64 + wco + c] = wp[kk];
      }
    }
    // --- stage features: 8 ci x 234-wide padded-linear window (stride 236)
    for (int e = tid; e < 8 * 236; e += 256) {
      int ci = e / 236, s = e - ci * 236;
      float v = 0.f;
      int pl = q0 - 53 + s;
      if (s < 234 && pl >= 0 && pl < 2704) {
        int r = pl / 52, cc = pl - r * 52;
        if (r >= 1 && r <= 50 && cc >= 1 && cc <= 50)
          v = feat[(size_t)(ci0 + ci) * NPOS + (r - 1) * 50 + (cc - 1)];
      }
      Fs[e] = v;
    }
    __syncthreads();
    // --- accumulate ---
    #pragma unroll
    for (int ci = 0; ci < 8; ++ci) {
      #pragma unroll
      for (int ky = 0; ky < 3; ++ky) {
        const int fb = ci * 236 + ky * 52 + tp * 8;
        float4 fa = *(const float4*)&Fs[fb];
        float4 fm = *(const float4*)&Fs[fb + 4];
        float2 fz = *(const float2*)&Fs[fb + 8];
        float f[10] = {fa.x, fa.y, fa.z, fa.w, fm.x, fm.y, fm.z, fm.w,
                       fz.x, fz.y};
        #pragma unroll
        for (int kx = 0; kx < 3; ++kx) {
          float4 w = *(const float4*)&Ws[(ci * 9 + ky * 3 + kx) * 64 + trt * 4];
          #pragma unroll
          for (int j = 0; j < 8; ++j) {
            acc[0][j] += w.x * f[j + kx];
            acc[1][j] += w.y * f[j + kx];
            acc[2][j] += w.z * f[j + kx];
            acc[3][j] += w.w * f[j + kx];
          }
        }
      }
    }
  }
  // --- write out (masked padded-linear -> image) ---
  #pragma unroll
  for (int j = 0; j < 8; ++j) {
    int pl = q0 + tp * 8 + j;
    int r = pl / 52, cc = pl - r * 52;
    if (r >= 1 && r <= 50 && cc >= 1 && cc <= 50) {
      int p = (r - 1) * 50 + (cc - 1);
      #pragma unroll
      for (int c = 0; c < 4; ++c)
        atomicAdd(&x[(size_t)(co0 + trt * 4 + c) * NPOS + p], acc[c][j]);
    }
  }
}

// ---------------- 2. 1x1 conv heads (36 reg + 18 cls channels) -------------
__global__ __launch_bounds__(256) void heads(
    const float* __restrict__ x, const float* __restrict__ Wreg,
    const float* __restrict__ breg, const float* __restrict__ Wcls,
    const float* __restrict__ bcls, float* __restrict__ ho) {
  int p = blockIdx.x * 64 + threadIdx.x;
  int ch = blockIdx.y * 4 + threadIdx.y;
  if (p >= NPOS || ch >= 54) return;
  const float* w = (ch < 36) ? (Wreg + (size_t)ch * 1024)
                             : (Wcls + (size_t)(ch - 36) * 1024);
  float a0 = 0.f, a1 = 0.f, a2 = 0.f, a3 = 0.f;
  for (int c = 0; c < 1024; c += 4) {
    a0 += w[c + 0] * x[(size_t)(c + 0) * NPOS + p];
    a1 += w[c + 1] * x[(size_t)(c + 1) * NPOS + p];
    a2 += w[c + 2] * x[(size_t)(c + 2) * NPOS + p];
    a3 += w[c + 3] * x[(size_t)(c + 3) * NPOS + p];
  }
  float bias = (ch < 36) ? breg[ch] : bcls[ch - 36];
  ho[p * 56 + ch] = (a0 + a1) + (a2 + a3) + bias;
}

// ---------------- 3. decode + min-size filter + sort keys ------------------
__global__ void decodek(const float* __restrict__ ho,
                        const float* __restrict__ anchors,
                        float4* __restrict__ roi,
                        unsigned long long* __restrict__ keys) {
  int i = blockIdx.x * 256 + threadIdx.x;   // grid covers exactly 32768
  if (i >= NBOX) { keys[i] = 0ull; return; }
  int p = i / 9, a = i % 9;
  const float* hp = ho + p * 56;
  float dy = hp[a * 4 + 0], dx = hp[a * 4 + 1];
  float dh = hp[a * 4 + 2], dw = hp[a * 4 + 3];
  float s = hp[36 + a * 2 + 1];
  float ay1 = anchors[i * 4 + 0], ax1 = anchors[i * 4 + 1];
  float ay2 = anchors[i * 4 + 2], ax2 = anchors[i * 4 + 3];
  float ahh = ay2 - ay1, aww = ax2 - ax1;
  float acy = ay1 + 0.5f * ahh, acx = ax1 + 0.5f * aww;
  float cy = dy * ahh + acy, cx = dx * aww + acx;
  float h = expf(dh) * ahh, w = expf(dw) * aww;
  float y1 = fminf(fmaxf(cy - 0.5f * h, 0.f), 800.f);
  float x1 = fminf(fmaxf(cx - 0.5f * w, 0.f), 800.f);
  float y2 = fminf(fmaxf(cy + 0.5f * h, 0.f), 800.f);
  float x2 = fminf(fmaxf(cx + 0.5f * w, 0.f), 800.f);
  bool valid = ((y2 - y1) >= 16.f) && ((x2 - x1) >= 16.f);
  float sc = valid ? s : -__builtin_inff();
  unsigned u = __float_as_uint(sc);
  u = (u & 0x80000000u) ? ~u : (u | 0x80000000u);  // monotone map
  keys[i] = ((unsigned long long)u << 32) |
            (unsigned long long)(0xFFFFFFFFu - (unsigned)i);
  roi[i] = make_float4(y1, x1, y2, x2);
}

// ---------------- 4. bitonic sort (descending), 32768 keys -----------------
__global__ __launch_bounds__(1024) void bitonic_local(unsigned long long* keys) {
  __shared__ unsigned long long s[4096];
  int t = threadIdx.x;
  size_t base = (size_t)blockIdx.x * 4096;
  for (int m = t; m < 4096; m += 1024) s[m] = keys[base + m];
  __syncthreads();
  for (int k = 2; k <= 4096; k <<= 1) {
    for (int j = k >> 1; j > 0; j >>= 1) {
      for (int m = t; m < 4096; m += 1024) {
        int l = m ^ j;
        if (l > m) {
          bool desc = (((base + (size_t)m) & (size_t)k) == 0);
          unsigned long long a = s[m], b = s[l];
          if (desc ? (a < b) : (a > b)) { s[m] = b; s[l] = a; }
        }
      }
      __syncthreads();
    }
  }
  for (int m = t; m < 4096; m += 1024) keys[base + m] = s[m];
}

__global__ __launch_bounds__(1024) void bitonic_merge_local(
    unsigned long long* keys, int k) {
  __shared__ unsigned long long s[4096];
  int t = threadIdx.x;
  size_t base = (size_t)blockIdx.x * 4096;
  for (int m = t; m < 4096; m += 1024) s[m] = keys[base + m];
  __syncthreads();
  for (int j = 2048; j > 0; j >>= 1) {
    for (int m = t; m < 4096; m += 1024) {
      int l = m ^ j;
      if (l > m) {
        bool desc = (((base + (size_t)m) & (size_t)k) == 0);
        unsigned long long a = s[m], b = s[l];
        if (desc ? (a < b) : (a > b)) { s[m] = b; s[l] = a; }
      }
    }
    __syncthreads();
  }
  for (int m = t; m < 4096; m += 1024) keys[base + m] = s[m];
}

__global__ void bitonic_global(unsigned long long* keys, int k, int j) {
  int m = blockIdx.x * 256 + threadIdx.x;
  int l = m ^ j;
  if (l > m) {
    bool desc = ((m & k) == 0);
    unsigned long long a = keys[m], b = keys[l];
    if (desc ? (a < b) : (a > b)) { keys[m] = b; keys[l] = a; }
  }
}

// ---------------- 5. gather sorted top-6000 boxes + valid flags ------------
__global__ void gatherk(const unsigned long long* __restrict__ keys,
                        const float4* __restrict__ roi,
                        float4* __restrict__ sbox, int* __restrict__ validArr) {
  int t = blockIdx.x * 256 + threadIdx.x;
  if (t >= NPRE) return;
  unsigned long long k = keys[t];
  unsigned u = (unsigned)(k >> 32);
  int valid = (u > 0x007FFFFFu) ? 1 : 0;
  float4 b = make_float4(0.f, 0.f, 0.f, 0.f);
  if (valid) {
    int idx = (int)(0xFFFFFFFFu - (unsigned)(k & 0xFFFFFFFFull));
    b = roi[idx];
  }
  sbox[t] = b;
  validArr[t] = valid;
}

// ---------------- 6. NMS suppression bitmask -------------------------------
__global__ __launch_bounds__(64) void nmsmask(
    const float4* __restrict__ sbox, unsigned long long* __restrict__ mask) {
  int rb = blockIdx.x, cb = blockIdx.y;
  int t = threadIdx.x;
  __shared__ float4 cbx[64];
  __shared__ float car[64];
  int jj = cb * 64 + t;
  float4 c = (jj < NPRE) ? sbox[jj] : make_float4(0.f, 0.f, 0.f, 0.f);
  cbx[t] = c;
  car[t] = (c.w - c.y + 1.f) * (c.z - c.x + 1.f);
  __syncthreads();
  int i = rb * 64 + t;
  if (i >= NPRE) return;
  float4 b = sbox[i];
  float ai = (b.w - b.y + 1.f) * (b.z - b.x + 1.f);
  unsigned long long bits = 0ull;
  int nj = min(64, NPRE - cb * 64);
  for (int j = 0; j < nj; ++j) {
    float4 cc = cbx[j];
    float yy1 = fmaxf(b.x, cc.x), xx1 = fmaxf(b.y, cc.y);
    float yy2 = fminf(b.z, cc.z), xx2 = fminf(b.w, cc.w);
    float inter = fmaxf(xx2 - xx1 + 1.f, 0.f) * fmaxf(yy2 - yy1 + 1.f, 0.f);
    float iou = inter / (ai + car[j] - inter);
    if (iou > 0.7f) bits |= (1ull << j);
  }
  mask[(size_t)i * NWORDS + cb] = bits;
}

// ---------------- 7. greedy scan (single wave) + output --------------------
__global__ __launch_bounds__(64) void nmsscan(
    const unsigned long long* __restrict__ mask,
    const int* __restrict__ validArr, const float4* __restrict__ sbox,
    float* __restrict__ out) {
  int t = threadIdx.x;
  __shared__ unsigned long long remv[NWORDS];
  __shared__ int keepIdx[NPOST];
  remv[t] = 0ull;
  if (t + 64 < NWORDS) remv[t + 64] = 0ull;
  __syncthreads();
  int nk = 0;
  for (int wb = 0; wb < NWORDS && nk < NPOST; ++wb) {
    int gi = wb * 64 + t;
    bool v = (gi < NPRE) && (validArr[gi] != 0);
    unsigned long long avail = __ballot(v);
    avail &= ~remv[wb];
    while (avail != 0ull && nk < NPOST) {
      int b = __ffsll((unsigned long long)avail) - 1;
      int i = wb * 64 + b;
      if (t == 0) keepIdx[nk] = i;
      nk++;
      const unsigned long long* row = mask + (size_t)i * NWORDS;
      remv[t] |= row[t];
      if (t + 64 < NWORDS) remv[t + 64] |= row[t + 64];
      __syncthreads();
      avail &= ~remv[wb];
    }
  }
  __syncthreads();
  for (int r = t; r < NPOST; r += 64) {
    float4 bx = make_float4(0.f, 0.f, 0.f, 0.f);
    if (r < nk) bx = sbox[keepIdx[r]];
    reinterpret_cast<float4*>(out)[r] = bx;
  }
}

// ---------------------------------------------------------------------------
extern "C" void kernel_launch(void* const* d_in, const int* in_sizes, int n_in,
                              void* d_out, int out_size, void* d_ws,
                              size_t ws_size, hipStream_t stream) {
  const float* feat    = (const float*)d_in[0];
  const float* anchors = (const float*)d_in[1];
  const float* W1      = (const float*)d_in[2];
  const float* b1      = (const float*)d_in[3];
  const float* Wreg    = (const float*)d_in[4];
  const float* breg    = (const float*)d_in[5];
  const float* Wcls    = (const float*)d_in[6];
  const float* bcls    = (const float*)d_in[7];

  char* ws = (char*)d_ws;
  float* x                   = (float*)(ws);                  // 10,240,000 B
  float* ho                  = (float*)(ws + 10240000);       //    560,000 B
  float4* roi                = (float4*)(ws + 10800000);      //    360,000 B
  unsigned long long* keys   = (unsigned long long*)(ws + 11160000); // 262,144 B
  float4* sbox               = (float4*)(ws + 11422144);      //     96,256 B
  int* validArr              = (int*)(ws + 11518400);         //     24,064 B
  unsigned long long* mask   = (unsigned long long*)(ws + 11542464); // 4,524,032 B
  float* out = (float*)d_out;

  initx<<<10000, 256, 0, stream>>>(b1, x);
  conv3x3_v2<<<dim3(22, 16, 4), 256, 0, stream>>>(feat, W1, x);
  heads<<<dim3(40, 14), dim3(64, 4), 0, stream>>>(x, Wreg, breg, Wcls, bcls, ho);
  decodek<<<128, 256, 0, stream>>>(ho, anchors, roi, keys);

  bitonic_local<<<8, 1024, 0, stream>>>(keys);
  for (int k = 8192; k <= NSORT; k <<= 1) {
    for (int j = k >> 1; j >= 4096; j >>= 1)
      bitonic_global<<<128, 256, 0, stream>>>(keys, k, j);
    bitonic_merge_local<<<8, 1024, 0, stream>>>(keys, k);
  }

  gatherk<<<24, 256, 0, stream>>>(keys, roi, sbox, validArr);
  nmsmask<<<dim3(NWORDS, NWORDS), 64, 0, stream>>>(sbox, mask);
  nmsscan<<<1, 64, 0, stream>>>(mask, validArr, sbox, out);
}